// Round 3
// baseline (101.709 us; speedup 1.0000x reference)
//
#include <hip/hip_runtime.h>

#define NC 4
#define CS 512
#define NS 256
#define HD 512
#define H  256
#define GAMMA_F 12.0f
#define PHASE_SCALE 62.83185307179586477f   // pi / 0.05

#define TI 32
#define TJ 32
#define KT 32

// Fully fused RotatE score, fp32 I/O (rounds 1-2 NaN = fp32 inputs were
// being read as bf16; reference arrays are jnp.float32).
// grid: 4 chunks * 16 head-tiles(32) * 8 tail-tiles(32) = 512 blocks, 256 thr
__global__ __launch_bounds__(256) void score_kernel(
    const float* __restrict__ heads,     // 2048 x 512
    const float* __restrict__ relations, // 2048 x 256
    const float* __restrict__ tails,     // 1024 x 512
    float* __restrict__ out)             // 4 x 512 x 256
{
    __shared__ float hr[TI][KT + 1];
    __shared__ float hi_[TI][KT + 1];
    __shared__ float tr[TJ][KT + 1];
    __shared__ float ti_[TJ][KT + 1];

    int bid = blockIdx.x;
    int c = bid >> 7;            // chunk
    int rem = bid & 127;
    int hTile = rem >> 3;        // 0..15
    int tTile = rem & 7;         // 0..7
    int hBase = c * CS + hTile * TI;   // global head row
    int tBase = c * NS + tTile * TJ;   // global tail row

    int tid = threadIdx.x;
    int tx = tid & 15;           // tail dim
    int ty = tid >> 4;           // head dim

    // staging assignment: 32 rows x 8 lanes x 4 elems (float4, 16B aligned)
    int lr = tid >> 3;           // 0..31
    int lk = (tid & 7) * 4;      // 0,4,...,28

    float acc00 = 0.f, acc01 = 0.f, acc10 = 0.f, acc11 = 0.f;

    for (int k0 = 0; k0 < H; k0 += KT) {
        // ---- global loads into regs first ----
        const float* hp = heads + (size_t)(hBase + lr) * HD + k0 + lk;
        float4 hre = *reinterpret_cast<const float4*>(hp);
        float4 him = *reinterpret_cast<const float4*>(hp + H);
        float4 rel = *reinterpret_cast<const float4*>(
            relations + (size_t)(hBase + lr) * H + k0 + lk);
        const float* tp = tails + (size_t)(tBase + lr) * HD + k0 + lk;
        float4 tre = *reinterpret_cast<const float4*>(tp);
        float4 tim = *reinterpret_cast<const float4*>(tp + H);

        __syncthreads();   // previous iteration's LDS reads complete

        // ---- rotate heads inline and stage to LDS ----
        {
            float s, cc;
            __sincosf(rel.x * PHASE_SCALE, &s, &cc);
            hr[lr][lk + 0] = hre.x * cc - him.x * s;
            hi_[lr][lk + 0] = hre.x * s + him.x * cc;
            __sincosf(rel.y * PHASE_SCALE, &s, &cc);
            hr[lr][lk + 1] = hre.y * cc - him.y * s;
            hi_[lr][lk + 1] = hre.y * s + him.y * cc;
            __sincosf(rel.z * PHASE_SCALE, &s, &cc);
            hr[lr][lk + 2] = hre.z * cc - him.z * s;
            hi_[lr][lk + 2] = hre.z * s + him.z * cc;
            __sincosf(rel.w * PHASE_SCALE, &s, &cc);
            hr[lr][lk + 3] = hre.w * cc - him.w * s;
            hi_[lr][lk + 3] = hre.w * s + him.w * cc;
        }
        tr[lr][lk + 0] = tre.x;  ti_[lr][lk + 0] = tim.x;
        tr[lr][lk + 1] = tre.y;  ti_[lr][lk + 1] = tim.y;
        tr[lr][lk + 2] = tre.z;  ti_[lr][lk + 2] = tim.z;
        tr[lr][lk + 3] = tre.w;  ti_[lr][lk + 3] = tim.w;

        __syncthreads();   // staging visible

        #pragma unroll
        for (int kk = 0; kk < KT; ++kk) {
            float h0r = hr[ty][kk],      h0i = hi_[ty][kk];
            float h1r = hr[ty + 16][kk], h1i = hi_[ty + 16][kk];
            float t0r = tr[tx][kk],      t0i = ti_[tx][kk];
            float t1r = tr[tx + 16][kk], t1i = ti_[tx + 16][kk];

            float dr, di;
            dr = h0r - t0r; di = h0i - t0i;
            acc00 += __builtin_amdgcn_sqrtf(dr * dr + di * di);
            dr = h0r - t1r; di = h0i - t1i;
            acc01 += __builtin_amdgcn_sqrtf(dr * dr + di * di);
            dr = h1r - t0r; di = h1i - t0i;
            acc10 += __builtin_amdgcn_sqrtf(dr * dr + di * di);
            dr = h1r - t1r; di = h1i - t1i;
            acc11 += __builtin_amdgcn_sqrtf(dr * dr + di * di);
        }
    }

    // epilogue: out[c][i_local][j_local] = GAMMA - acc
    int i0 = hTile * TI + ty;
    int j0 = tTile * TJ + tx;
    size_t base = (size_t)c * CS * NS;
    out[base + (size_t)(i0)      * NS + j0]      = GAMMA_F - acc00;
    out[base + (size_t)(i0)      * NS + j0 + 16] = GAMMA_F - acc01;
    out[base + (size_t)(i0 + 16) * NS + j0]      = GAMMA_F - acc10;
    out[base + (size_t)(i0 + 16) * NS + j0 + 16] = GAMMA_F - acc11;
}

extern "C" void kernel_launch(void* const* d_in, const int* in_sizes, int n_in,
                              void* d_out, int out_size, void* d_ws, size_t ws_size,
                              hipStream_t stream) {
    (void)in_sizes; (void)n_in; (void)d_ws; (void)ws_size; (void)out_size;
    const float* heads = (const float*)d_in[0];
    const float* rels  = (const float*)d_in[1];
    const float* tails = (const float*)d_in[2];

    score_kernel<<<512, 256, 0, stream>>>(heads, rels, tails, (float*)d_out);
}

// Round 4
// 98.816 us; speedup vs baseline: 1.0293x; 1.0293x over previous
//
#include <hip/hip_runtime.h>

#define NC 4
#define CS 512
#define NS 256
#define HD 512
#define H  256
#define GAMMA_F 12.0f
#define PHASE_SCALE 62.83185307179586477f   // pi / 0.05

#define KT 16   // k-steps per staging round

// Round 4: LDS-issue-rate fix.
//  - 4x4 register micro-tile (16 outputs/thread): LDS reads/output 2 -> 0.5
//  - (re,im) interleaved float2 in LDS -> ds_read_b64 instead of 2x b32
//  - K-split by 4 (64-k slice per block) to keep 512 blocks / 2048 waves
//  - partials combined with atomicAdd into zero-memset d_out (ks==0 adds GAMMA)
// grid: 4 chunks * 4 kslices * 8 hTiles(64) * 4 tTiles(64) = 512 blocks, 256 thr
__global__ __launch_bounds__(256, 2) void score_kernel(
    const float* __restrict__ heads,     // 2048 x 512
    const float* __restrict__ relations, // 2048 x 256
    const float* __restrict__ tails,     // 1024 x 512
    float* __restrict__ out)             // 4 x 512 x 256 (pre-zeroed)
{
    __shared__ float2 sh[64][KT + 1];   // rotated head (re,im), +1 pad
    __shared__ float2 st[64][KT + 1];   // tail (re,im), +1 pad

    int bid = blockIdx.x;
    int c    = bid >> 7;          // chunk
    int rem  = bid & 127;
    int ks   = rem >> 5;          // k-slice 0..3
    int rem2 = rem & 31;
    int hT   = rem2 >> 2;         // 0..7
    int tT   = rem2 & 3;          // 0..3

    int hBase = c * CS + hT * 64;     // global head row
    int tBase = c * NS + tT * 64;     // global tail row
    int kSlice = ks * 64;             // k range [kSlice, kSlice+64)

    int tid = threadIdx.x;
    int tx = tid & 15;            // tail micro index
    int ty = tid >> 4;            // head micro index

    // staging: 64 rows x 4 lanes x 4 k-elems (float4)
    int srow = tid >> 2;          // 0..63
    int sk   = (tid & 3) * 4;     // 0,4,8,12

    float acc[4][4];
    #pragma unroll
    for (int m = 0; m < 4; ++m)
        #pragma unroll
        for (int n = 0; n < 4; ++n) acc[m][n] = 0.f;

    for (int r = 0; r < 64 / KT; ++r) {
        int kBase = kSlice + r * KT;

        // ---- global loads into regs ----
        const float* hp = heads + (size_t)(hBase + srow) * HD + kBase + sk;
        float4 hre = *reinterpret_cast<const float4*>(hp);
        float4 him = *reinterpret_cast<const float4*>(hp + H);
        float4 rel = *reinterpret_cast<const float4*>(
            relations + (size_t)(hBase + srow) * H + kBase + sk);
        const float* tp = tails + (size_t)(tBase + srow) * HD + kBase + sk;
        float4 tre = *reinterpret_cast<const float4*>(tp);
        float4 tim = *reinterpret_cast<const float4*>(tp + H);

        __syncthreads();   // previous round's LDS reads complete

        // ---- rotate heads inline, stage interleaved (re,im) ----
        {
            float s, cc;
            __sincosf(rel.x * PHASE_SCALE, &s, &cc);
            sh[srow][sk + 0] = make_float2(hre.x * cc - him.x * s,
                                           hre.x * s + him.x * cc);
            __sincosf(rel.y * PHASE_SCALE, &s, &cc);
            sh[srow][sk + 1] = make_float2(hre.y * cc - him.y * s,
                                           hre.y * s + him.y * cc);
            __sincosf(rel.z * PHASE_SCALE, &s, &cc);
            sh[srow][sk + 2] = make_float2(hre.z * cc - him.z * s,
                                           hre.z * s + him.z * cc);
            __sincosf(rel.w * PHASE_SCALE, &s, &cc);
            sh[srow][sk + 3] = make_float2(hre.w * cc - him.w * s,
                                           hre.w * s + him.w * cc);
        }
        st[srow][sk + 0] = make_float2(tre.x, tim.x);
        st[srow][sk + 1] = make_float2(tre.y, tim.y);
        st[srow][sk + 2] = make_float2(tre.z, tim.z);
        st[srow][sk + 3] = make_float2(tre.w, tim.w);

        __syncthreads();   // staging visible

        #pragma unroll
        for (int kk = 0; kk < KT; ++kk) {
            float2 h0 = sh[ty     ][kk];
            float2 h1 = sh[ty + 16][kk];
            float2 h2 = sh[ty + 32][kk];
            float2 h3 = sh[ty + 48][kk];
            float2 t0 = st[tx     ][kk];
            float2 t1 = st[tx + 16][kk];
            float2 t2 = st[tx + 32][kk];
            float2 t3 = st[tx + 48][kk];
            float2 hv[4] = {h0, h1, h2, h3};
            float2 tv[4] = {t0, t1, t2, t3};
            #pragma unroll
            for (int m = 0; m < 4; ++m) {
                #pragma unroll
                for (int n = 0; n < 4; ++n) {
                    float dr = hv[m].x - tv[n].x;
                    float di = hv[m].y - tv[n].y;
                    acc[m][n] += __builtin_amdgcn_sqrtf(dr * dr + di * di);
                }
            }
        }
    }

    // epilogue: atomic-accumulate partial (slice 0 contributes GAMMA)
    float base_add = (ks == 0) ? GAMMA_F : 0.f;
    size_t cbase = (size_t)c * CS * NS;
    #pragma unroll
    for (int m = 0; m < 4; ++m) {
        int i0 = hT * 64 + ty + 16 * m;
        #pragma unroll
        for (int n = 0; n < 4; ++n) {
            int j0 = tT * 64 + tx + 16 * n;
            atomicAdd(&out[cbase + (size_t)i0 * NS + j0], base_add - acc[m][n]);
        }
    }
}

extern "C" void kernel_launch(void* const* d_in, const int* in_sizes, int n_in,
                              void* d_out, int out_size, void* d_ws, size_t ws_size,
                              hipStream_t stream) {
    (void)in_sizes; (void)n_in; (void)d_ws; (void)ws_size;
    const float* heads = (const float*)d_in[0];
    const float* rels  = (const float*)d_in[1];
    const float* tails = (const float*)d_in[2];

    // zero-init output (atomic accumulation target); graph-capturable
    hipMemsetAsync(d_out, 0, (size_t)out_size * sizeof(float), stream);
    score_kernel<<<512, 256, 0, stream>>>(heads, rels, tails, (float*)d_out);
}

// Round 5
// 98.369 us; speedup vs baseline: 1.0340x; 1.0045x over previous
//
#include <hip/hip_runtime.h>

#define NC 4
#define CS 512
#define NS 256
#define HD 512
#define H  256
#define GAMMA_F 12.0f
#define PHASE_SCALE 62.83185307179586477f   // pi / 0.05

#define KT 16   // k-steps per staging round

// Round 5: round-4 compute structure, atomics removed (atomic tail theory:
// 64 atomics/cacheline serialized in L2 ~ 25us). Split-K partials go to d_ws
// as 4 planes; tiny reduce kernel folds them with GAMMA.
// grid: 4 chunks * 4 kslices * 8 hTiles(64) * 4 tTiles(64) = 512 blocks, 256 thr
__global__ __launch_bounds__(256, 2) void score_partial(
    const float* __restrict__ heads,     // 2048 x 512
    const float* __restrict__ relations, // 2048 x 256
    const float* __restrict__ tails,     // 1024 x 512
    float* __restrict__ part)            // 4 planes of [4][512][256]
{
    __shared__ float2 sh[64][KT + 1];   // rotated head (re,im), +1 pad
    __shared__ float2 st[64][KT + 1];   // tail (re,im), +1 pad

    int bid = blockIdx.x;
    int c    = bid >> 7;          // chunk
    int rem  = bid & 127;
    int ks   = rem >> 5;          // k-slice 0..3
    int rem2 = rem & 31;
    int hT   = rem2 >> 2;         // 0..7
    int tT   = rem2 & 3;          // 0..3

    int hBase = c * CS + hT * 64;     // global head row
    int tBase = c * NS + tT * 64;     // global tail row
    int kSlice = ks * 64;             // k range [kSlice, kSlice+64)

    int tid = threadIdx.x;
    int tx = tid & 15;            // tail micro index
    int ty = tid >> 4;            // head micro index

    // staging: 64 rows x 4 lanes x 4 k-elems (float4)
    int srow = tid >> 2;          // 0..63
    int sk   = (tid & 3) * 4;     // 0,4,8,12

    float acc[4][4];
    #pragma unroll
    for (int m = 0; m < 4; ++m)
        #pragma unroll
        for (int n = 0; n < 4; ++n) acc[m][n] = 0.f;

    for (int r = 0; r < 64 / KT; ++r) {
        int kBase = kSlice + r * KT;

        // ---- global loads into regs ----
        const float* hp = heads + (size_t)(hBase + srow) * HD + kBase + sk;
        float4 hre = *reinterpret_cast<const float4*>(hp);
        float4 him = *reinterpret_cast<const float4*>(hp + H);
        float4 rel = *reinterpret_cast<const float4*>(
            relations + (size_t)(hBase + srow) * H + kBase + sk);
        const float* tp = tails + (size_t)(tBase + srow) * HD + kBase + sk;
        float4 tre = *reinterpret_cast<const float4*>(tp);
        float4 tim = *reinterpret_cast<const float4*>(tp + H);

        __syncthreads();   // previous round's LDS reads complete

        // ---- rotate heads inline, stage interleaved (re,im) ----
        {
            float s, cc;
            __sincosf(rel.x * PHASE_SCALE, &s, &cc);
            sh[srow][sk + 0] = make_float2(hre.x * cc - him.x * s,
                                           hre.x * s + him.x * cc);
            __sincosf(rel.y * PHASE_SCALE, &s, &cc);
            sh[srow][sk + 1] = make_float2(hre.y * cc - him.y * s,
                                           hre.y * s + him.y * cc);
            __sincosf(rel.z * PHASE_SCALE, &s, &cc);
            sh[srow][sk + 2] = make_float2(hre.z * cc - him.z * s,
                                           hre.z * s + him.z * cc);
            __sincosf(rel.w * PHASE_SCALE, &s, &cc);
            sh[srow][sk + 3] = make_float2(hre.w * cc - him.w * s,
                                           hre.w * s + him.w * cc);
        }
        st[srow][sk + 0] = make_float2(tre.x, tim.x);
        st[srow][sk + 1] = make_float2(tre.y, tim.y);
        st[srow][sk + 2] = make_float2(tre.z, tim.z);
        st[srow][sk + 3] = make_float2(tre.w, tim.w);

        __syncthreads();   // staging visible

        #pragma unroll
        for (int kk = 0; kk < KT; ++kk) {
            float2 hv[4], tv[4];
            hv[0] = sh[ty     ][kk];
            hv[1] = sh[ty + 16][kk];
            hv[2] = sh[ty + 32][kk];
            hv[3] = sh[ty + 48][kk];
            tv[0] = st[tx     ][kk];
            tv[1] = st[tx + 16][kk];
            tv[2] = st[tx + 32][kk];
            tv[3] = st[tx + 48][kk];
            #pragma unroll
            for (int m = 0; m < 4; ++m) {
                #pragma unroll
                for (int n = 0; n < 4; ++n) {
                    float dr = hv[m].x - tv[n].x;
                    float di = hv[m].y - tv[n].y;
                    acc[m][n] += __builtin_amdgcn_sqrtf(dr * dr + di * di);
                }
            }
        }
    }

    // epilogue: plain stores of this k-slice's partial plane
    float* plane = part + (size_t)ks * (NC * CS * NS);
    size_t cbase = (size_t)c * CS * NS;
    #pragma unroll
    for (int m = 0; m < 4; ++m) {
        int i0 = hT * 64 + ty + 16 * m;
        #pragma unroll
        for (int n = 0; n < 4; ++n) {
            int j0 = tT * 64 + tx + 16 * n;
            plane[cbase + (size_t)i0 * NS + j0] = acc[m][n];
        }
    }
}

// out = GAMMA - (p0+p1+p2+p3); 131072 threads, one float4 each
__global__ __launch_bounds__(256) void reduce_kernel(
    const float* __restrict__ part, float* __restrict__ out)
{
    const int PLANE = NC * CS * NS;   // 524288
    int idx = (blockIdx.x * 256 + threadIdx.x) * 4;
    float4 p0 = *reinterpret_cast<const float4*>(part + idx);
    float4 p1 = *reinterpret_cast<const float4*>(part + PLANE + idx);
    float4 p2 = *reinterpret_cast<const float4*>(part + 2 * PLANE + idx);
    float4 p3 = *reinterpret_cast<const float4*>(part + 3 * PLANE + idx);
    float4 r;
    r.x = GAMMA_F - (p0.x + p1.x + p2.x + p3.x);
    r.y = GAMMA_F - (p0.y + p1.y + p2.y + p3.y);
    r.z = GAMMA_F - (p0.z + p1.z + p2.z + p3.z);
    r.w = GAMMA_F - (p0.w + p1.w + p2.w + p3.w);
    *reinterpret_cast<float4*>(out + idx) = r;
}

extern "C" void kernel_launch(void* const* d_in, const int* in_sizes, int n_in,
                              void* d_out, int out_size, void* d_ws, size_t ws_size,
                              hipStream_t stream) {
    (void)in_sizes; (void)n_in; (void)ws_size; (void)out_size;
    const float* heads = (const float*)d_in[0];
    const float* rels  = (const float*)d_in[1];
    const float* tails = (const float*)d_in[2];
    float* part = (float*)d_ws;   // 4 planes x 2 MB = 8 MB

    score_partial<<<512, 256, 0, stream>>>(heads, rels, tails, part);
    reduce_kernel<<<512, 256, 0, stream>>>(part, (float*)d_out);
}